// Round 23
// baseline (948.291 us; speedup 1.0000x reference)
//
#include <hip/hip_runtime.h>
#include <hip/hip_fp16.h>

#define HP 192
#define WP 192
#define NPIX (HP * WP)   // 36864
#define SG 24
#define KSTRU 72         // smK/smV row stride in ushorts (f16): 144 B
#define PI_STRU 12       // smpi16 row stride in uints: 48 B
#define PRE16 33         // preLds16 row stride in uints (f16 pairs)
#define XSTR 36          // qkv xh row stride in uints: 144 B

typedef _Float16 h2 __attribute__((ext_vector_type(2)));

__device__ __forceinline__ unsigned int h2pack(float a, float b) {
  h2 r;
  r[0] = (_Float16)a;
  r[1] = (_Float16)b;
  return __builtin_bit_cast(unsigned int, r);
}
__device__ __forceinline__ h2 ash2(unsigned int u) {
  return __builtin_bit_cast(h2, u);
}
__device__ __forceinline__ __half2 asH2(unsigned int u) {
  return __builtin_bit_cast(__half2, u);
}
__device__ __forceinline__ unsigned int asU(__half2 v) {
  return __builtin_bit_cast(unsigned int, v);
}

// ---------------- Kernel 1: QKV projection, x read ONCE ----------------------
// grid 576, block 768 = 64 px x 12 col-groups (jg = tid/64, wave-uniform).
// x slice staged to LDS as packed f16 (8 KB, stride 144 B); weights via
// wave-uniform VECTOR loads (L1 broadcast -- not the r15 scalar-pipe trap).
// HBM traffic: 9.4 MB x + 14 MB writes (~4 us floor); 6912 waves for TLP.
__global__ __launch_bounds__(768) void qkv_kernel(
    const float* __restrict__ x,
    const float* __restrict__ w_qk,
    const float* __restrict__ w_v,
    unsigned int* __restrict__ qb16, unsigned int* __restrict__ kb16,
    unsigned int* __restrict__ vb16) {
  __shared__ __align__(16) unsigned int xh[64 * XSTR];  // 9 KB (pad 36)
  const int tid = threadIdx.x;
  const int px0 = blockIdx.x * 64;

  // stage x: 64 px x 32 ch-pairs, coalesced over px (lanes = consecutive px)
  for (int i = tid; i < 64 * 32; i += 768) {
    const int px = i & 63, cp = i >> 6;
    const float a = x[(2 * cp) * NPIX + px0 + px];
    const float b = x[(2 * cp + 1) * NPIX + px0 + px];
    xh[px * XSTR + cp] = h2pack(a, b);
  }
  __syncthreads();

  const int px = tid & 63;
  const int jg = tid >> 6;  // 0..11, exactly wave-uniform (64 | wave)
  const int pix = px0 + px;
  const int j0 = jg * 16;

  // read this pixel's x row from LDS (8 x b128)
  const unsigned int* xrow = xh + px * XSTR;
  uint4 xr[8];
#pragma unroll
  for (int i = 0; i < 8; ++i) xr[i] = *(const uint4*)(xrow + 4 * i);

  float acc[16];
#pragma unroll
  for (int j = 0; j < 16; ++j) acc[j] = 0.f;

  const float* wbase;
  int wstride, wcol;
  if (jg < 8) {
    wbase = w_qk; wstride = 128; wcol = j0;
  } else {
    wbase = w_v; wstride = 64; wcol = j0 - 128;
  }
#pragma unroll
  for (int u = 0; u < 8; ++u) {
    const uint4 xu = xr[u];
#pragma unroll
    for (int q = 0; q < 4; ++q) {
      const unsigned int pv = (&xu.x)[q];
      const h2 hh = ash2(pv);
      const float xc0 = (float)hh[0];
      const float xc1 = (float)hh[1];
      const int cp = u * 4 + q;
      const float* w0 = wbase + (2 * cp) * wstride + wcol;
      const float* w1 = wbase + (2 * cp + 1) * wstride + wcol;
#pragma unroll
      for (int j = 0; j < 16; ++j)
        acc[j] = fmaf(xc1, w1[j], fmaf(xc0, w0[j], acc[j]));
    }
  }

  unsigned int* dst;
  float mul = 1.0f;
  if (jg < 4) {
    dst = qb16 + (size_t)pix * 32 + j0 / 2;
    mul = 0.25f * 1.44269504089f;  // hd^-0.5 * log2(e)
  } else if (jg < 8) {
    dst = kb16 + (size_t)pix * 32 + (j0 - 64) / 2;
  } else {
    dst = vb16 + (size_t)pix * 32 + (j0 - 128) / 2;
  }
#pragma unroll
  for (int j = 0; j < 8; ++j)
    dst[j] = h2pack(acc[2 * j] * mul, acc[2 * j + 1] * mul);
}

__device__ __forceinline__ float pi_val(const float* __restrict__ sims, int th,
                                        int tw, int r, int c, int s) {
  const int dh = s / 3, dw = s - dh * 3;
  const int shi = th + dh - 1, swj = tw + dw - 1;
  if (shi < 0 || shi >= SG || swj < 0 || swj >= SG || r < 0 || r >= HP ||
      c < 0 || c >= WP)
    return 0.f;
  return sims[((size_t)(r * WP + c)) * (SG * SG) + shi * SG + swj];
}

// ---------------- Kernel 2: attention + fused output projection (r22) --------
__global__ __launch_bounds__(512) void attn_kernel(
    const unsigned int* __restrict__ qb16, const unsigned int* __restrict__ kb16,
    const unsigned int* __restrict__ vb16, const float* __restrict__ sims,
    const float* __restrict__ w_proj, float* __restrict__ out) {
  __shared__ __align__(16) unsigned short smK[196 * KSTRU];
  __shared__ __align__(16) unsigned short smV[196 * KSTRU];
  __shared__ __align__(16) unsigned int smpi16[196 * PI_STRU];
  __shared__ __align__(16) unsigned int preLds16[64 * PRE16];
  const int tile = blockIdx.x;
  const int th = tile / 24, tw = tile % 24;
  const int rowBase = th * 8 - 3, colBase = tw * 8 - 3;
  const int tid = threadIdx.x;

  // ---- stage K and V tiles: straight uint4 copies (f16-packed) ----
  for (int i = tid; i < 196 * 8; i += 512) {
    const int loc = i >> 3, c4 = i & 7;
    const int rl = loc / 14, cl = loc - rl * 14;
    const int r = rowBase + rl, c = colBase + cl;
    uint4 k4 = make_uint4(0u, 0u, 0u, 0u);
    uint4 v4 = make_uint4(0u, 0u, 0u, 0u);
    if (r >= 0 && r < HP && c >= 0 && c < WP) {
      const size_t base = (size_t)(r * WP + c) * 32 + (c4 << 2);
      k4 = *(const uint4*)(kb16 + base);
      v4 = *(const uint4*)(vb16 + base);
    }
    *(uint4*)(smK + loc * KSTRU + (c4 << 3)) = k4;
    *(uint4*)(smV + loc * KSTRU + (c4 << 3)) = v4;
  }
  // ---- stage pi table as f16 pairs: [loc][5 uints] (s8 padded) ----
  for (int i = tid; i < 196 * 5; i += 512) {
    const int loc = i / 5, sp = i - loc * 5;
    const int rl = loc / 14, cl = loc - rl * 14;
    const int r = rowBase + rl, c = colBase + cl;
    const int s0 = sp * 2;
    const float v0 = pi_val(sims, th, tw, r, c, s0);
    const float v1 = (s0 + 1 < 9) ? pi_val(sims, th, tw, r, c, s0 + 1) : 0.f;
    smpi16[loc * PI_STRU + sp] = h2pack(v0, v1);
  }
  __syncthreads();

  const int split = tid & 1;
  const int head = (tid >> 1) & 3;
  const int pl = tid >> 3;  // pixel-in-tile 0..63
  const int py = pl >> 3, px = pl & 7;
  const int h = th * 8 + py, w = tw * 8 + px;
  const int pix = h * WP + w;
  int hs = h - 3;
  hs = hs < 0 ? 0 : (hs > HP - 7 ? HP - 7 : hs);
  int wsb = w - 3;
  wsb = wsb < 0 ? 0 : (wsb > WP - 7 ? WP - 7 : wsb);
  const int rl0 = hs - rowBase;   // 0..7
  const int cl0 = wsb - colBase;  // 0..7
  const int hq = head << 4;       // head base in halves
  const int hu = head << 3;       // head base in uints

  const uint4 qa = *(const uint4*)(qb16 + (size_t)pix * 32 + hu);
  const uint4 qc = *(const uint4*)(qb16 + (size_t)pix * 32 + hu + 4);
  const h2 qh0 = ash2(qa.x), qh1 = ash2(qa.y), qh2 = ash2(qa.z),
           qh3 = ash2(qa.w);
  const h2 qh4 = ash2(qc.x), qh5 = ash2(qc.y), qh6 = ash2(qc.z),
           qh7 = ash2(qc.w);

#define DOT8P(t, kp)                                          \
  {                                                           \
    const uint4 ka = *(const uint4*)(kp);                     \
    const uint4 kc = *(const uint4*)((kp) + 8);               \
    float t0 = 0.f, t1 = 0.f;                                 \
    t0 = __builtin_amdgcn_fdot2(ash2(ka.x), qh0, t0, false);  \
    t0 = __builtin_amdgcn_fdot2(ash2(ka.y), qh1, t0, false);  \
    t0 = __builtin_amdgcn_fdot2(ash2(ka.z), qh2, t0, false);  \
    t0 = __builtin_amdgcn_fdot2(ash2(ka.w), qh3, t0, false);  \
    t1 = __builtin_amdgcn_fdot2(ash2(kc.x), qh4, t1, false);  \
    t1 = __builtin_amdgcn_fdot2(ash2(kc.y), qh5, t1, false);  \
    t1 = __builtin_amdgcn_fdot2(ash2(kc.z), qh6, t1, false);  \
    t1 = __builtin_amdgcn_fdot2(ash2(kc.w), qh7, t1, false);  \
    t = t0 + t1;                                              \
  }

  // ---- pass 1 (FULL unroll): e -> ev[7][4]; partial S, packed D9 ----
  float ev[7][4];
  __half2 D9h0 = __float2half2_rn(0.f), D9h1 = __float2half2_rn(0.f);
  __half2 D9h2 = __float2half2_rn(0.f), D9h3 = __float2half2_rn(0.f);
  float D8 = 0.f, S = 0.f;
#pragma unroll
  for (int kh = 0; kh < 7; ++kh) {
    const int rowloc = (rl0 + kh) * 14 + cl0 + split;
    const unsigned short* krow = smK + rowloc * KSTRU + hq;
    const unsigned int* prow = smpi16 + rowloc * PI_STRU;
#pragma unroll
    for (int j = 0; j < 4; ++j) {
      if (j < 3 || split == 0) {  // kw = 2j+split must be < 7
        float t;
        DOT8P(t, krow + j * (2 * KSTRU))
        const float e = exp2f(t);
        ev[kh][j] = e;
        S += e;
        const unsigned int* pp = prow + j * (2 * PI_STRU);
        const uint4 pu = *(const uint4*)pp;
        const unsigned int p8u = pp[4];
        const __half2 e2 = __float2half2_rn(e);
        D9h0 = __hfma2(e2, asH2(pu.x), D9h0);
        D9h1 = __hfma2(e2, asH2(pu.y), D9h1);
        D9h2 = __hfma2(e2, asH2(pu.z), D9h2);
        D9h3 = __hfma2(e2, asH2(pu.w), D9h3);
        D8 = fmaf(e, (float)ash2(p8u)[0], D8);
      } else {
        ev[kh][j] = 0.f;
      }
    }
  }
#undef DOT8P
  S += __shfl_xor(S, 1);
  D8 += __shfl_xor(D8, 1);
#define COMBH(D) D = __hadd2(D, asH2(__shfl_xor(asU(D), 1)));
  COMBH(D9h0) COMBH(D9h1) COMBH(D9h2) COMBH(D9h3)
#undef COMBH

  // ---- coef_s = ws[s] / (D[s] + 1e-10*S); packed for pass 2 ----
  h2 ch0, ch1, ch2, ch3;
  float c8;
  {
    const unsigned int* pp =
        smpi16 + ((h - rowBase) * 14 + (w - colBase)) * PI_STRU;
    const uint4 pu = *(const uint4*)pp;
    const unsigned int p8u = pp[4];
    const h2 w0 = ash2(pu.x), w1 = ash2(pu.y), w2 = ash2(pu.z),
             w3 = ash2(pu.w);
    const float epsS = 1e-10f * S;
    ch0[0] = (_Float16)((float)w0[0] / (__low2float(D9h0) + epsS));
    ch0[1] = (_Float16)((float)w0[1] / (__high2float(D9h0) + epsS));
    ch1[0] = (_Float16)((float)w1[0] / (__low2float(D9h1) + epsS));
    ch1[1] = (_Float16)((float)w1[1] / (__high2float(D9h1) + epsS));
    ch2[0] = (_Float16)((float)w2[0] / (__low2float(D9h2) + epsS));
    ch2[1] = (_Float16)((float)w2[1] / (__high2float(D9h2) + epsS));
    ch3[0] = (_Float16)((float)w3[0] / (__low2float(D9h3) + epsS));
    ch3[1] = (_Float16)((float)w3[1] / (__high2float(D9h3) + epsS));
    c8 = (float)ash2(p8u)[0] / (D8 + epsS);
  }

  // ---- pass 2 (FULL unroll): NO K/exp2 -- a2 = ev*tc; o += a2*V ----
  __half2 o0 = __float2half2_rn(0.f), o1 = __float2half2_rn(0.f);
  __half2 o2 = __float2half2_rn(0.f), o3 = __float2half2_rn(0.f);
  __half2 o4 = __float2half2_rn(0.f), o5 = __float2half2_rn(0.f);
  __half2 o6 = __float2half2_rn(0.f), o7 = __float2half2_rn(0.f);
#pragma unroll
  for (int kh = 0; kh < 7; ++kh) {
    const int rowloc = (rl0 + kh) * 14 + cl0 + split;
    const unsigned short* vrow = smV + rowloc * KSTRU + hq;
    const unsigned int* prow = smpi16 + rowloc * PI_STRU;
#pragma unroll
    for (int j = 0; j < 4; ++j) {
      if (j < 3 || split == 0) {
        const unsigned int* pp = prow + j * (2 * PI_STRU);
        const uint4 pu = *(const uint4*)pp;
        const unsigned int p8u = pp[4];
        float tA = __builtin_amdgcn_fdot2(ash2(pu.x), ch0, 0.f, false);
        tA = __builtin_amdgcn_fdot2(ash2(pu.y), ch1, tA, false);
        float tB = __builtin_amdgcn_fdot2(ash2(pu.z), ch2, 0.f, false);
        tB = __builtin_amdgcn_fdot2(ash2(pu.w), ch3, tB, false);
        const float tc = (tA + tB) + c8 * (float)ash2(p8u)[0];
        const __half2 a2 = __float2half2_rn(ev[kh][j] * tc);
        const unsigned short* vp = vrow + j * (2 * KSTRU);
        const uint4 va = *(const uint4*)vp;
        const uint4 vc = *(const uint4*)(vp + 8);
        o0 = __hfma2(a2, asH2(va.x), o0);
        o1 = __hfma2(a2, asH2(va.y), o1);
        o2 = __hfma2(a2, asH2(va.z), o2);
        o3 = __hfma2(a2, asH2(va.w), o3);
        o4 = __hfma2(a2, asH2(vc.x), o4);
        o5 = __hfma2(a2, asH2(vc.y), o5);
        o6 = __hfma2(a2, asH2(vc.z), o6);
        o7 = __hfma2(a2, asH2(vc.w), o7);
      }
    }
  }

  // ---- combine lane pair (packed); write to preLds16 ----
#define COMBO(x) x = __hadd2(x, asH2(__shfl_xor(asU(x), 1)));
  COMBO(o0) COMBO(o1) COMBO(o2) COMBO(o3)
  COMBO(o4) COMBO(o5) COMBO(o6) COMBO(o7)
#undef COMBO
  {
    unsigned int* pw = preLds16 + pl * PRE16 + hu + split * 4;
    pw[0] = asU(split ? o4 : o0);
    pw[1] = asU(split ? o5 : o1);
    pw[2] = asU(split ? o6 : o2);
    pw[3] = asU(split ? o7 : o3);
  }
  __syncthreads();

  // ---- fused output projection: 8 groups x 8 cols, w_proj scalar ----------
  const int jb2 = __builtin_amdgcn_readfirstlane(tid >> 6);  // wave-uniform
  const int px2 = tid & 63;
  const int j0 = jb2 * 8;
  const int opix = (th * 8 + (px2 >> 3)) * WP + tw * 8 + (px2 & 7);
  float acc[8];
#pragma unroll
  for (int j = 0; j < 8; ++j) acc[j] = 0.f;
  const unsigned int* prow = preLds16 + px2 * PRE16;
#pragma unroll 8
  for (int cp = 0; cp < 32; ++cp) {
    const h2 hh = ash2(prow[cp]);
    const float xc0 = (float)hh[0];
    const float xc1 = (float)hh[1];
    const float* w0 = w_proj + (2 * cp) * 64 + j0;      // scalar rows
    const float* w1 = w_proj + (2 * cp + 1) * 64 + j0;
#pragma unroll
    for (int j = 0; j < 8; ++j)
      acc[j] = fmaf(xc1, w1[j], fmaf(xc0, w0[j], acc[j]));
  }
#pragma unroll
  for (int j = 0; j < 8; ++j) out[(size_t)(j0 + j) * NPIX + opix] = acc[j];
}

extern "C" void kernel_launch(void* const* d_in, const int* in_sizes, int n_in,
                              void* d_out, int out_size, void* d_ws,
                              size_t ws_size, hipStream_t stream) {
  const float* x = (const float*)d_in[0];
  const float* sims = (const float*)d_in[1];
  const float* w_qk = (const float*)d_in[2];
  const float* w_v = (const float*)d_in[3];
  const float* w_proj = (const float*)d_in[4];
  float* out = (float*)d_out;

  unsigned int* qb16 = (unsigned int*)d_ws;
  unsigned int* kb16 = qb16 + (size_t)NPIX * 32;
  unsigned int* vb16 = kb16 + (size_t)NPIX * 32;

  qkv_kernel<<<dim3(576), 768, 0, stream>>>(x, w_qk, w_v, qb16, kb16, vb16);
  attn_kernel<<<dim3(576), 512, 0, stream>>>(qb16, kb16, vb16, sims, w_proj,
                                             out);
}

// Round 24
// 924.797 us; speedup vs baseline: 1.0254x; 1.0254x over previous
//
#include <hip/hip_runtime.h>
#include <hip/hip_fp16.h>

#define HP 192
#define WP 192
#define NPIX (HP * WP)   // 36864
#define SG 24
#define KSTRU 72         // smK/smV row stride in ushorts (f16): 144 B
#define PI_STRU 12       // smpi16 row stride in uints: 48 B
#define PRE16 33         // preLds16 row stride in uints (f16 pairs)
#define XSTR 36          // qkv xh row stride in uints: 144 B

typedef _Float16 h2 __attribute__((ext_vector_type(2)));

__device__ __forceinline__ unsigned int h2pack(float a, float b) {
  h2 r;
  r[0] = (_Float16)a;
  r[1] = (_Float16)b;
  return __builtin_bit_cast(unsigned int, r);
}
__device__ __forceinline__ h2 ash2(unsigned int u) {
  return __builtin_bit_cast(h2, u);
}
__device__ __forceinline__ __half2 asH2(unsigned int u) {
  return __builtin_bit_cast(__half2, u);
}
__device__ __forceinline__ unsigned int asU(__half2 v) {
  return __builtin_bit_cast(unsigned int, v);
}

// ---------------- Kernel 1: QKV projection, x read ONCE ----------------------
// grid 576, block 768 = 64 px x 12 col-groups (jg = tid/64, wave-uniform).
// r23's version scratch-exploded because (&xu.x)[q] (address-of a vector
// component) forced xr[] to private memory. Fixed: explicit .x/.y/.z/.w via
// macro -- no pointers into registers.
__global__ __launch_bounds__(768) void qkv_kernel(
    const float* __restrict__ x,
    const float* __restrict__ w_qk,
    const float* __restrict__ w_v,
    unsigned int* __restrict__ qb16, unsigned int* __restrict__ kb16,
    unsigned int* __restrict__ vb16) {
  __shared__ __align__(16) unsigned int xh[64 * XSTR];  // 9 KB (pad 36)
  const int tid = threadIdx.x;
  const int px0 = blockIdx.x * 64;

  // stage x: 64 px x 32 ch-pairs, coalesced over px (lanes = consecutive px)
  for (int i = tid; i < 64 * 32; i += 768) {
    const int px = i & 63, cp = i >> 6;
    const float a = x[(2 * cp) * NPIX + px0 + px];
    const float b = x[(2 * cp + 1) * NPIX + px0 + px];
    xh[px * XSTR + cp] = h2pack(a, b);
  }
  __syncthreads();

  const int px = tid & 63;
  const int jg = tid >> 6;  // 0..11, exactly wave-uniform (64 | wave)
  const int pix = px0 + px;
  const int j0 = jg * 16;

  // read this pixel's x row from LDS (8 x b128) into named uint4s
  const unsigned int* xrow = xh + px * XSTR;
  const uint4 x0 = *(const uint4*)(xrow + 0);
  const uint4 x1 = *(const uint4*)(xrow + 4);
  const uint4 x2 = *(const uint4*)(xrow + 8);
  const uint4 x3 = *(const uint4*)(xrow + 12);
  const uint4 x4 = *(const uint4*)(xrow + 16);
  const uint4 x5 = *(const uint4*)(xrow + 20);
  const uint4 x6 = *(const uint4*)(xrow + 24);
  const uint4 x7 = *(const uint4*)(xrow + 28);

  float acc[16];
#pragma unroll
  for (int j = 0; j < 16; ++j) acc[j] = 0.f;

  const float* wbase;
  int wstride, wcol;
  if (jg < 8) {
    wbase = w_qk; wstride = 128; wcol = j0;
  } else {
    wbase = w_v; wstride = 64; wcol = j0 - 128;
  }

// one x channel-pair (packed uint PV, channel-pair index CP) -> 16 cols
#define QKV_PAIR(PV, CP)                                                  \
  {                                                                       \
    const h2 hh = ash2(PV);                                               \
    const float xc0 = (float)hh[0];                                       \
    const float xc1 = (float)hh[1];                                       \
    const float* w0 = wbase + (2 * (CP)) * wstride + wcol;                \
    const float* w1 = wbase + (2 * (CP) + 1) * wstride + wcol;            \
    _Pragma("unroll")                                                     \
    for (int j = 0; j < 16; ++j)                                          \
      acc[j] = fmaf(xc1, w1[j], fmaf(xc0, w0[j], acc[j]));                \
  }

  QKV_PAIR(x0.x, 0)  QKV_PAIR(x0.y, 1)  QKV_PAIR(x0.z, 2)  QKV_PAIR(x0.w, 3)
  QKV_PAIR(x1.x, 4)  QKV_PAIR(x1.y, 5)  QKV_PAIR(x1.z, 6)  QKV_PAIR(x1.w, 7)
  QKV_PAIR(x2.x, 8)  QKV_PAIR(x2.y, 9)  QKV_PAIR(x2.z, 10) QKV_PAIR(x2.w, 11)
  QKV_PAIR(x3.x, 12) QKV_PAIR(x3.y, 13) QKV_PAIR(x3.z, 14) QKV_PAIR(x3.w, 15)
  QKV_PAIR(x4.x, 16) QKV_PAIR(x4.y, 17) QKV_PAIR(x4.z, 18) QKV_PAIR(x4.w, 19)
  QKV_PAIR(x5.x, 20) QKV_PAIR(x5.y, 21) QKV_PAIR(x5.z, 22) QKV_PAIR(x5.w, 23)
  QKV_PAIR(x6.x, 24) QKV_PAIR(x6.y, 25) QKV_PAIR(x6.z, 26) QKV_PAIR(x6.w, 27)
  QKV_PAIR(x7.x, 28) QKV_PAIR(x7.y, 29) QKV_PAIR(x7.z, 30) QKV_PAIR(x7.w, 31)
#undef QKV_PAIR

  unsigned int* dst;
  float mul = 1.0f;
  if (jg < 4) {
    dst = qb16 + (size_t)pix * 32 + j0 / 2;
    mul = 0.25f * 1.44269504089f;  // hd^-0.5 * log2(e)
  } else if (jg < 8) {
    dst = kb16 + (size_t)pix * 32 + (j0 - 64) / 2;
  } else {
    dst = vb16 + (size_t)pix * 32 + (j0 - 128) / 2;
  }
#pragma unroll
  for (int j = 0; j < 8; ++j)
    dst[j] = h2pack(acc[2 * j] * mul, acc[2 * j + 1] * mul);
}

__device__ __forceinline__ float pi_val(const float* __restrict__ sims, int th,
                                        int tw, int r, int c, int s) {
  const int dh = s / 3, dw = s - dh * 3;
  const int shi = th + dh - 1, swj = tw + dw - 1;
  if (shi < 0 || shi >= SG || swj < 0 || swj >= SG || r < 0 || r >= HP ||
      c < 0 || c >= WP)
    return 0.f;
  return sims[((size_t)(r * WP + c)) * (SG * SG) + shi * SG + swj];
}

// ---------------- Kernel 2: attention + fused output projection (r22) --------
__global__ __launch_bounds__(512) void attn_kernel(
    const unsigned int* __restrict__ qb16, const unsigned int* __restrict__ kb16,
    const unsigned int* __restrict__ vb16, const float* __restrict__ sims,
    const float* __restrict__ w_proj, float* __restrict__ out) {
  __shared__ __align__(16) unsigned short smK[196 * KSTRU];
  __shared__ __align__(16) unsigned short smV[196 * KSTRU];
  __shared__ __align__(16) unsigned int smpi16[196 * PI_STRU];
  __shared__ __align__(16) unsigned int preLds16[64 * PRE16];
  const int tile = blockIdx.x;
  const int th = tile / 24, tw = tile % 24;
  const int rowBase = th * 8 - 3, colBase = tw * 8 - 3;
  const int tid = threadIdx.x;

  // ---- stage K and V tiles: straight uint4 copies (f16-packed) ----
  for (int i = tid; i < 196 * 8; i += 512) {
    const int loc = i >> 3, c4 = i & 7;
    const int rl = loc / 14, cl = loc - rl * 14;
    const int r = rowBase + rl, c = colBase + cl;
    uint4 k4 = make_uint4(0u, 0u, 0u, 0u);
    uint4 v4 = make_uint4(0u, 0u, 0u, 0u);
    if (r >= 0 && r < HP && c >= 0 && c < WP) {
      const size_t base = (size_t)(r * WP + c) * 32 + (c4 << 2);
      k4 = *(const uint4*)(kb16 + base);
      v4 = *(const uint4*)(vb16 + base);
    }
    *(uint4*)(smK + loc * KSTRU + (c4 << 3)) = k4;
    *(uint4*)(smV + loc * KSTRU + (c4 << 3)) = v4;
  }
  // ---- stage pi table as f16 pairs: [loc][5 uints] (s8 padded) ----
  for (int i = tid; i < 196 * 5; i += 512) {
    const int loc = i / 5, sp = i - loc * 5;
    const int rl = loc / 14, cl = loc - rl * 14;
    const int r = rowBase + rl, c = colBase + cl;
    const int s0 = sp * 2;
    const float v0 = pi_val(sims, th, tw, r, c, s0);
    const float v1 = (s0 + 1 < 9) ? pi_val(sims, th, tw, r, c, s0 + 1) : 0.f;
    smpi16[loc * PI_STRU + sp] = h2pack(v0, v1);
  }
  __syncthreads();

  const int split = tid & 1;
  const int head = (tid >> 1) & 3;
  const int pl = tid >> 3;  // pixel-in-tile 0..63
  const int py = pl >> 3, px = pl & 7;
  const int h = th * 8 + py, w = tw * 8 + px;
  const int pix = h * WP + w;
  int hs = h - 3;
  hs = hs < 0 ? 0 : (hs > HP - 7 ? HP - 7 : hs);
  int wsb = w - 3;
  wsb = wsb < 0 ? 0 : (wsb > WP - 7 ? WP - 7 : wsb);
  const int rl0 = hs - rowBase;   // 0..7
  const int cl0 = wsb - colBase;  // 0..7
  const int hq = head << 4;       // head base in halves
  const int hu = head << 3;       // head base in uints

  const uint4 qa = *(const uint4*)(qb16 + (size_t)pix * 32 + hu);
  const uint4 qc = *(const uint4*)(qb16 + (size_t)pix * 32 + hu + 4);
  const h2 qh0 = ash2(qa.x), qh1 = ash2(qa.y), qh2 = ash2(qa.z),
           qh3 = ash2(qa.w);
  const h2 qh4 = ash2(qc.x), qh5 = ash2(qc.y), qh6 = ash2(qc.z),
           qh7 = ash2(qc.w);

#define DOT8P(t, kp)                                          \
  {                                                           \
    const uint4 ka = *(const uint4*)(kp);                     \
    const uint4 kc = *(const uint4*)((kp) + 8);               \
    float t0 = 0.f, t1 = 0.f;                                 \
    t0 = __builtin_amdgcn_fdot2(ash2(ka.x), qh0, t0, false);  \
    t0 = __builtin_amdgcn_fdot2(ash2(ka.y), qh1, t0, false);  \
    t0 = __builtin_amdgcn_fdot2(ash2(ka.z), qh2, t0, false);  \
    t0 = __builtin_amdgcn_fdot2(ash2(ka.w), qh3, t0, false);  \
    t1 = __builtin_amdgcn_fdot2(ash2(kc.x), qh4, t1, false);  \
    t1 = __builtin_amdgcn_fdot2(ash2(kc.y), qh5, t1, false);  \
    t1 = __builtin_amdgcn_fdot2(ash2(kc.z), qh6, t1, false);  \
    t1 = __builtin_amdgcn_fdot2(ash2(kc.w), qh7, t1, false);  \
    t = t0 + t1;                                              \
  }

  // ---- pass 1 (FULL unroll): e -> ev[7][4]; partial S, packed D9 ----
  float ev[7][4];
  __half2 D9h0 = __float2half2_rn(0.f), D9h1 = __float2half2_rn(0.f);
  __half2 D9h2 = __float2half2_rn(0.f), D9h3 = __float2half2_rn(0.f);
  float D8 = 0.f, S = 0.f;
#pragma unroll
  for (int kh = 0; kh < 7; ++kh) {
    const int rowloc = (rl0 + kh) * 14 + cl0 + split;
    const unsigned short* krow = smK + rowloc * KSTRU + hq;
    const unsigned int* prow = smpi16 + rowloc * PI_STRU;
#pragma unroll
    for (int j = 0; j < 4; ++j) {
      if (j < 3 || split == 0) {  // kw = 2j+split must be < 7
        float t;
        DOT8P(t, krow + j * (2 * KSTRU))
        const float e = exp2f(t);
        ev[kh][j] = e;
        S += e;
        const unsigned int* pp = prow + j * (2 * PI_STRU);
        const uint4 pu = *(const uint4*)pp;
        const unsigned int p8u = pp[4];
        const __half2 e2 = __float2half2_rn(e);
        D9h0 = __hfma2(e2, asH2(pu.x), D9h0);
        D9h1 = __hfma2(e2, asH2(pu.y), D9h1);
        D9h2 = __hfma2(e2, asH2(pu.z), D9h2);
        D9h3 = __hfma2(e2, asH2(pu.w), D9h3);
        D8 = fmaf(e, (float)ash2(p8u)[0], D8);
      } else {
        ev[kh][j] = 0.f;
      }
    }
  }
#undef DOT8P
  S += __shfl_xor(S, 1);
  D8 += __shfl_xor(D8, 1);
#define COMBH(D) D = __hadd2(D, asH2(__shfl_xor(asU(D), 1)));
  COMBH(D9h0) COMBH(D9h1) COMBH(D9h2) COMBH(D9h3)
#undef COMBH

  // ---- coef_s = ws[s] / (D[s] + 1e-10*S); packed for pass 2 ----
  h2 ch0, ch1, ch2, ch3;
  float c8;
  {
    const unsigned int* pp =
        smpi16 + ((h - rowBase) * 14 + (w - colBase)) * PI_STRU;
    const uint4 pu = *(const uint4*)pp;
    const unsigned int p8u = pp[4];
    const h2 w0 = ash2(pu.x), w1 = ash2(pu.y), w2 = ash2(pu.z),
             w3 = ash2(pu.w);
    const float epsS = 1e-10f * S;
    ch0[0] = (_Float16)((float)w0[0] / (__low2float(D9h0) + epsS));
    ch0[1] = (_Float16)((float)w0[1] / (__high2float(D9h0) + epsS));
    ch1[0] = (_Float16)((float)w1[0] / (__low2float(D9h1) + epsS));
    ch1[1] = (_Float16)((float)w1[1] / (__high2float(D9h1) + epsS));
    ch2[0] = (_Float16)((float)w2[0] / (__low2float(D9h2) + epsS));
    ch2[1] = (_Float16)((float)w2[1] / (__high2float(D9h2) + epsS));
    ch3[0] = (_Float16)((float)w3[0] / (__low2float(D9h3) + epsS));
    ch3[1] = (_Float16)((float)w3[1] / (__high2float(D9h3) + epsS));
    c8 = (float)ash2(p8u)[0] / (D8 + epsS);
  }

  // ---- pass 2 (FULL unroll): NO K/exp2 -- a2 = ev*tc; o += a2*V ----
  __half2 o0 = __float2half2_rn(0.f), o1 = __float2half2_rn(0.f);
  __half2 o2 = __float2half2_rn(0.f), o3 = __float2half2_rn(0.f);
  __half2 o4 = __float2half2_rn(0.f), o5 = __float2half2_rn(0.f);
  __half2 o6 = __float2half2_rn(0.f), o7 = __float2half2_rn(0.f);
#pragma unroll
  for (int kh = 0; kh < 7; ++kh) {
    const int rowloc = (rl0 + kh) * 14 + cl0 + split;
    const unsigned short* vrow = smV + rowloc * KSTRU + hq;
    const unsigned int* prow = smpi16 + rowloc * PI_STRU;
#pragma unroll
    for (int j = 0; j < 4; ++j) {
      if (j < 3 || split == 0) {
        const unsigned int* pp = prow + j * (2 * PI_STRU);
        const uint4 pu = *(const uint4*)pp;
        const unsigned int p8u = pp[4];
        float tA = __builtin_amdgcn_fdot2(ash2(pu.x), ch0, 0.f, false);
        tA = __builtin_amdgcn_fdot2(ash2(pu.y), ch1, tA, false);
        float tB = __builtin_amdgcn_fdot2(ash2(pu.z), ch2, 0.f, false);
        tB = __builtin_amdgcn_fdot2(ash2(pu.w), ch3, tB, false);
        const float tc = (tA + tB) + c8 * (float)ash2(p8u)[0];
        const __half2 a2 = __float2half2_rn(ev[kh][j] * tc);
        const unsigned short* vp = vrow + j * (2 * KSTRU);
        const uint4 va = *(const uint4*)vp;
        const uint4 vc = *(const uint4*)(vp + 8);
        o0 = __hfma2(a2, asH2(va.x), o0);
        o1 = __hfma2(a2, asH2(va.y), o1);
        o2 = __hfma2(a2, asH2(va.z), o2);
        o3 = __hfma2(a2, asH2(va.w), o3);
        o4 = __hfma2(a2, asH2(vc.x), o4);
        o5 = __hfma2(a2, asH2(vc.y), o5);
        o6 = __hfma2(a2, asH2(vc.z), o6);
        o7 = __hfma2(a2, asH2(vc.w), o7);
      }
    }
  }

  // ---- combine lane pair (packed); write to preLds16 ----
#define COMBO(x) x = __hadd2(x, asH2(__shfl_xor(asU(x), 1)));
  COMBO(o0) COMBO(o1) COMBO(o2) COMBO(o3)
  COMBO(o4) COMBO(o5) COMBO(o6) COMBO(o7)
#undef COMBO
  {
    unsigned int* pw = preLds16 + pl * PRE16 + hu + split * 4;
    pw[0] = asU(split ? o4 : o0);
    pw[1] = asU(split ? o5 : o1);
    pw[2] = asU(split ? o6 : o2);
    pw[3] = asU(split ? o7 : o3);
  }
  __syncthreads();

  // ---- fused output projection: 8 groups x 8 cols, w_proj scalar ----------
  const int jb2 = __builtin_amdgcn_readfirstlane(tid >> 6);  // wave-uniform
  const int px2 = tid & 63;
  const int j0 = jb2 * 8;
  const int opix = (th * 8 + (px2 >> 3)) * WP + tw * 8 + (px2 & 7);
  float acc[8];
#pragma unroll
  for (int j = 0; j < 8; ++j) acc[j] = 0.f;
  const unsigned int* prow = preLds16 + px2 * PRE16;
#pragma unroll 8
  for (int cp = 0; cp < 32; ++cp) {
    const h2 hh = ash2(prow[cp]);
    const float xc0 = (float)hh[0];
    const float xc1 = (float)hh[1];
    const float* w0 = w_proj + (2 * cp) * 64 + j0;      // scalar rows
    const float* w1 = w_proj + (2 * cp + 1) * 64 + j0;
#pragma unroll
    for (int j = 0; j < 8; ++j)
      acc[j] = fmaf(xc1, w1[j], fmaf(xc0, w0[j], acc[j]));
  }
#pragma unroll
  for (int j = 0; j < 8; ++j) out[(size_t)(j0 + j) * NPIX + opix] = acc[j];
}

extern "C" void kernel_launch(void* const* d_in, const int* in_sizes, int n_in,
                              void* d_out, int out_size, void* d_ws,
                              size_t ws_size, hipStream_t stream) {
  const float* x = (const float*)d_in[0];
  const float* sims = (const float*)d_in[1];
  const float* w_qk = (const float*)d_in[2];
  const float* w_v = (const float*)d_in[3];
  const float* w_proj = (const float*)d_in[4];
  float* out = (float*)d_out;

  unsigned int* qb16 = (unsigned int*)d_ws;
  unsigned int* kb16 = qb16 + (size_t)NPIX * 32;
  unsigned int* vb16 = kb16 + (size_t)NPIX * 32;

  qkv_kernel<<<dim3(576), 768, 0, stream>>>(x, w_qk, w_v, qb16, kb16, vb16);
  attn_kernel<<<dim3(576), 512, 0, stream>>>(qb16, kb16, vb16, sims, w_proj,
                                             out);
}

// Round 25
// 96.438 us; speedup vs baseline: 9.8332x; 9.5895x over previous
//
#include <hip/hip_runtime.h>
#include <hip/hip_fp16.h>

#define HP 192
#define WP 192
#define NPIX (HP * WP)   // 36864
#define SG 24
#define KSTRU 72         // smK/smV row stride in ushorts (f16): 144 B
#define PI_STRU 12       // smpi16 row stride in uints: 48 B
#define PRE16 33         // preLds16 row stride in uints (f16 pairs)
#define XSTR 36          // qkv xh row stride in uints: 144 B

typedef _Float16 h2 __attribute__((ext_vector_type(2)));

__device__ __forceinline__ unsigned int h2pack(float a, float b) {
  h2 r;
  r[0] = (_Float16)a;
  r[1] = (_Float16)b;
  return __builtin_bit_cast(unsigned int, r);
}
__device__ __forceinline__ h2 ash2(unsigned int u) {
  return __builtin_bit_cast(h2, u);
}
__device__ __forceinline__ __half2 asH2(unsigned int u) {
  return __builtin_bit_cast(__half2, u);
}
__device__ __forceinline__ unsigned int asU(__half2 v) {
  return __builtin_bit_cast(unsigned int, v);
}

// ---------------- Kernel 1: QKV projection, x staged in LDS ------------------
// grid (3, 576), block 256 = 64 px x 4 wave-uniform col-groups. Each block
// stages its 64 pixels' x as packed f16 (9 KB) and covers 4 of the 12
// col-groups (jg = part*4 + wave). Compute body = r22's proven no-spill shape
// (acc[16], full 64-ch unroll, vector weight loads); x unpacked from LDS.
// x HBM traffic 113 -> 28 MB.
__global__ __launch_bounds__(256) void qkv_kernel(
    const float* __restrict__ x,
    const float* __restrict__ w_qk,
    const float* __restrict__ w_v,
    unsigned int* __restrict__ qb16, unsigned int* __restrict__ kb16,
    unsigned int* __restrict__ vb16) {
  __shared__ __align__(16) unsigned int xh[64 * XSTR];  // 9 KB (pad 36)
  const int tid = threadIdx.x;
  const int part = blockIdx.x;       // 0..2  (fast dim -> L2 locality)
  const int px0 = blockIdx.y * 64;

  // stage x: 64 px x 32 ch-pairs, coalesced over px
  for (int i = tid; i < 64 * 32; i += 256) {
    const int px = i & 63, cp = i >> 6;
    const float a = x[(2 * cp) * NPIX + px0 + px];
    const float b = x[(2 * cp + 1) * NPIX + px0 + px];
    xh[px * XSTR + cp] = h2pack(a, b);
  }
  __syncthreads();

  const int px = tid & 63;
  const int jg = part * 4 + (tid >> 6);  // 0..11, wave-uniform
  const int pix = px0 + px;
  const int j0 = jg * 16;
  const unsigned int* xrow = xh + px * XSTR;

  float acc[16];
#pragma unroll
  for (int j = 0; j < 16; ++j) acc[j] = 0.f;

  if (jg < 8) {
#pragma unroll
    for (int cp = 0; cp < 32; ++cp) {
      const h2 hh = ash2(xrow[cp]);
      const float xc0 = (float)hh[0];
      const float xc1 = (float)hh[1];
      const float* w0 = w_qk + (2 * cp) * 128 + j0;
      const float* w1 = w_qk + (2 * cp + 1) * 128 + j0;
#pragma unroll
      for (int j = 0; j < 16; ++j)
        acc[j] = fmaf(xc1, w1[j], fmaf(xc0, w0[j], acc[j]));
    }
  } else {
#pragma unroll
    for (int cp = 0; cp < 32; ++cp) {
      const h2 hh = ash2(xrow[cp]);
      const float xc0 = (float)hh[0];
      const float xc1 = (float)hh[1];
      const float* w0 = w_v + (2 * cp) * 64 + (j0 - 128);
      const float* w1 = w_v + (2 * cp + 1) * 64 + (j0 - 128);
#pragma unroll
      for (int j = 0; j < 16; ++j)
        acc[j] = fmaf(xc1, w1[j], fmaf(xc0, w0[j], acc[j]));
    }
  }

  unsigned int* dst;
  float mul = 1.0f;
  if (jg < 4) {
    dst = qb16 + (size_t)pix * 32 + j0 / 2;
    mul = 0.25f * 1.44269504089f;  // hd^-0.5 * log2(e)
  } else if (jg < 8) {
    dst = kb16 + (size_t)pix * 32 + (j0 - 64) / 2;
  } else {
    dst = vb16 + (size_t)pix * 32 + (j0 - 128) / 2;
  }
#pragma unroll
  for (int j = 0; j < 8; ++j)
    dst[j] = h2pack(acc[2 * j] * mul, acc[2 * j + 1] * mul);
}

__device__ __forceinline__ float pi_val(const float* __restrict__ sims, int th,
                                        int tw, int r, int c, int s) {
  const int dh = s / 3, dw = s - dh * 3;
  const int shi = th + dh - 1, swj = tw + dw - 1;
  if (shi < 0 || shi >= SG || swj < 0 || swj >= SG || r < 0 || r >= HP ||
      c < 0 || c >= WP)
    return 0.f;
  return sims[((size_t)(r * WP + c)) * (SG * SG) + shi * SG + swj];
}

// ---------------- Kernel 2: attention + fused output projection (r22) --------
__global__ __launch_bounds__(512) void attn_kernel(
    const unsigned int* __restrict__ qb16, const unsigned int* __restrict__ kb16,
    const unsigned int* __restrict__ vb16, const float* __restrict__ sims,
    const float* __restrict__ w_proj, float* __restrict__ out) {
  __shared__ __align__(16) unsigned short smK[196 * KSTRU];
  __shared__ __align__(16) unsigned short smV[196 * KSTRU];
  __shared__ __align__(16) unsigned int smpi16[196 * PI_STRU];
  __shared__ __align__(16) unsigned int preLds16[64 * PRE16];
  const int tile = blockIdx.x;
  const int th = tile / 24, tw = tile % 24;
  const int rowBase = th * 8 - 3, colBase = tw * 8 - 3;
  const int tid = threadIdx.x;

  // ---- stage K and V tiles: straight uint4 copies (f16-packed) ----
  for (int i = tid; i < 196 * 8; i += 512) {
    const int loc = i >> 3, c4 = i & 7;
    const int rl = loc / 14, cl = loc - rl * 14;
    const int r = rowBase + rl, c = colBase + cl;
    uint4 k4 = make_uint4(0u, 0u, 0u, 0u);
    uint4 v4 = make_uint4(0u, 0u, 0u, 0u);
    if (r >= 0 && r < HP && c >= 0 && c < WP) {
      const size_t base = (size_t)(r * WP + c) * 32 + (c4 << 2);
      k4 = *(const uint4*)(kb16 + base);
      v4 = *(const uint4*)(vb16 + base);
    }
    *(uint4*)(smK + loc * KSTRU + (c4 << 3)) = k4;
    *(uint4*)(smV + loc * KSTRU + (c4 << 3)) = v4;
  }
  // ---- stage pi table as f16 pairs: [loc][5 uints] (s8 padded) ----
  for (int i = tid; i < 196 * 5; i += 512) {
    const int loc = i / 5, sp = i - loc * 5;
    const int rl = loc / 14, cl = loc - rl * 14;
    const int r = rowBase + rl, c = colBase + cl;
    const int s0 = sp * 2;
    const float v0 = pi_val(sims, th, tw, r, c, s0);
    const float v1 = (s0 + 1 < 9) ? pi_val(sims, th, tw, r, c, s0 + 1) : 0.f;
    smpi16[loc * PI_STRU + sp] = h2pack(v0, v1);
  }
  __syncthreads();

  const int split = tid & 1;
  const int head = (tid >> 1) & 3;
  const int pl = tid >> 3;  // pixel-in-tile 0..63
  const int py = pl >> 3, px = pl & 7;
  const int h = th * 8 + py, w = tw * 8 + px;
  const int pix = h * WP + w;
  int hs = h - 3;
  hs = hs < 0 ? 0 : (hs > HP - 7 ? HP - 7 : hs);
  int wsb = w - 3;
  wsb = wsb < 0 ? 0 : (wsb > WP - 7 ? WP - 7 : wsb);
  const int rl0 = hs - rowBase;   // 0..7
  const int cl0 = wsb - colBase;  // 0..7
  const int hq = head << 4;       // head base in halves
  const int hu = head << 3;       // head base in uints

  const uint4 qa = *(const uint4*)(qb16 + (size_t)pix * 32 + hu);
  const uint4 qc = *(const uint4*)(qb16 + (size_t)pix * 32 + hu + 4);
  const h2 qh0 = ash2(qa.x), qh1 = ash2(qa.y), qh2 = ash2(qa.z),
           qh3 = ash2(qa.w);
  const h2 qh4 = ash2(qc.x), qh5 = ash2(qc.y), qh6 = ash2(qc.z),
           qh7 = ash2(qc.w);

#define DOT8P(t, kp)                                          \
  {                                                           \
    const uint4 ka = *(const uint4*)(kp);                     \
    const uint4 kc = *(const uint4*)((kp) + 8);               \
    float t0 = 0.f, t1 = 0.f;                                 \
    t0 = __builtin_amdgcn_fdot2(ash2(ka.x), qh0, t0, false);  \
    t0 = __builtin_amdgcn_fdot2(ash2(ka.y), qh1, t0, false);  \
    t0 = __builtin_amdgcn_fdot2(ash2(ka.z), qh2, t0, false);  \
    t0 = __builtin_amdgcn_fdot2(ash2(ka.w), qh3, t0, false);  \
    t1 = __builtin_amdgcn_fdot2(ash2(kc.x), qh4, t1, false);  \
    t1 = __builtin_amdgcn_fdot2(ash2(kc.y), qh5, t1, false);  \
    t1 = __builtin_amdgcn_fdot2(ash2(kc.z), qh6, t1, false);  \
    t1 = __builtin_amdgcn_fdot2(ash2(kc.w), qh7, t1, false);  \
    t = t0 + t1;                                              \
  }

  // ---- pass 1 (FULL unroll): e -> ev[7][4]; partial S, packed D9 ----
  float ev[7][4];
  __half2 D9h0 = __float2half2_rn(0.f), D9h1 = __float2half2_rn(0.f);
  __half2 D9h2 = __float2half2_rn(0.f), D9h3 = __float2half2_rn(0.f);
  float D8 = 0.f, S = 0.f;
#pragma unroll
  for (int kh = 0; kh < 7; ++kh) {
    const int rowloc = (rl0 + kh) * 14 + cl0 + split;
    const unsigned short* krow = smK + rowloc * KSTRU + hq;
    const unsigned int* prow = smpi16 + rowloc * PI_STRU;
#pragma unroll
    for (int j = 0; j < 4; ++j) {
      if (j < 3 || split == 0) {  // kw = 2j+split must be < 7
        float t;
        DOT8P(t, krow + j * (2 * KSTRU))
        const float e = exp2f(t);
        ev[kh][j] = e;
        S += e;
        const unsigned int* pp = prow + j * (2 * PI_STRU);
        const uint4 pu = *(const uint4*)pp;
        const unsigned int p8u = pp[4];
        const __half2 e2 = __float2half2_rn(e);
        D9h0 = __hfma2(e2, asH2(pu.x), D9h0);
        D9h1 = __hfma2(e2, asH2(pu.y), D9h1);
        D9h2 = __hfma2(e2, asH2(pu.z), D9h2);
        D9h3 = __hfma2(e2, asH2(pu.w), D9h3);
        D8 = fmaf(e, (float)ash2(p8u)[0], D8);
      } else {
        ev[kh][j] = 0.f;
      }
    }
  }
#undef DOT8P
  S += __shfl_xor(S, 1);
  D8 += __shfl_xor(D8, 1);
#define COMBH(D) D = __hadd2(D, asH2(__shfl_xor(asU(D), 1)));
  COMBH(D9h0) COMBH(D9h1) COMBH(D9h2) COMBH(D9h3)
#undef COMBH

  // ---- coef_s = ws[s] / (D[s] + 1e-10*S); packed for pass 2 ----
  h2 ch0, ch1, ch2, ch3;
  float c8;
  {
    const unsigned int* pp =
        smpi16 + ((h - rowBase) * 14 + (w - colBase)) * PI_STRU;
    const uint4 pu = *(const uint4*)pp;
    const unsigned int p8u = pp[4];
    const h2 w0 = ash2(pu.x), w1 = ash2(pu.y), w2 = ash2(pu.z),
             w3 = ash2(pu.w);
    const float epsS = 1e-10f * S;
    ch0[0] = (_Float16)((float)w0[0] / (__low2float(D9h0) + epsS));
    ch0[1] = (_Float16)((float)w0[1] / (__high2float(D9h0) + epsS));
    ch1[0] = (_Float16)((float)w1[0] / (__low2float(D9h1) + epsS));
    ch1[1] = (_Float16)((float)w1[1] / (__high2float(D9h1) + epsS));
    ch2[0] = (_Float16)((float)w2[0] / (__low2float(D9h2) + epsS));
    ch2[1] = (_Float16)((float)w2[1] / (__high2float(D9h2) + epsS));
    ch3[0] = (_Float16)((float)w3[0] / (__low2float(D9h3) + epsS));
    ch3[1] = (_Float16)((float)w3[1] / (__high2float(D9h3) + epsS));
    c8 = (float)ash2(p8u)[0] / (D8 + epsS);
  }

  // ---- pass 2 (FULL unroll): NO K/exp2 -- a2 = ev*tc; o += a2*V ----
  __half2 o0 = __float2half2_rn(0.f), o1 = __float2half2_rn(0.f);
  __half2 o2 = __float2half2_rn(0.f), o3 = __float2half2_rn(0.f);
  __half2 o4 = __float2half2_rn(0.f), o5 = __float2half2_rn(0.f);
  __half2 o6 = __float2half2_rn(0.f), o7 = __float2half2_rn(0.f);
#pragma unroll
  for (int kh = 0; kh < 7; ++kh) {
    const int rowloc = (rl0 + kh) * 14 + cl0 + split;
    const unsigned short* vrow = smV + rowloc * KSTRU + hq;
    const unsigned int* prow = smpi16 + rowloc * PI_STRU;
#pragma unroll
    for (int j = 0; j < 4; ++j) {
      if (j < 3 || split == 0) {
        const unsigned int* pp = prow + j * (2 * PI_STRU);
        const uint4 pu = *(const uint4*)pp;
        const unsigned int p8u = pp[4];
        float tA = __builtin_amdgcn_fdot2(ash2(pu.x), ch0, 0.f, false);
        tA = __builtin_amdgcn_fdot2(ash2(pu.y), ch1, tA, false);
        float tB = __builtin_amdgcn_fdot2(ash2(pu.z), ch2, 0.f, false);
        tB = __builtin_amdgcn_fdot2(ash2(pu.w), ch3, tB, false);
        const float tc = (tA + tB) + c8 * (float)ash2(p8u)[0];
        const __half2 a2 = __float2half2_rn(ev[kh][j] * tc);
        const unsigned short* vp = vrow + j * (2 * KSTRU);
        const uint4 va = *(const uint4*)vp;
        const uint4 vc = *(const uint4*)(vp + 8);
        o0 = __hfma2(a2, asH2(va.x), o0);
        o1 = __hfma2(a2, asH2(va.y), o1);
        o2 = __hfma2(a2, asH2(va.z), o2);
        o3 = __hfma2(a2, asH2(va.w), o3);
        o4 = __hfma2(a2, asH2(vc.x), o4);
        o5 = __hfma2(a2, asH2(vc.y), o5);
        o6 = __hfma2(a2, asH2(vc.z), o6);
        o7 = __hfma2(a2, asH2(vc.w), o7);
      }
    }
  }

  // ---- combine lane pair (packed); write to preLds16 ----
#define COMBO(x) x = __hadd2(x, asH2(__shfl_xor(asU(x), 1)));
  COMBO(o0) COMBO(o1) COMBO(o2) COMBO(o3)
  COMBO(o4) COMBO(o5) COMBO(o6) COMBO(o7)
#undef COMBO
  {
    unsigned int* pw = preLds16 + pl * PRE16 + hu + split * 4;
    pw[0] = asU(split ? o4 : o0);
    pw[1] = asU(split ? o5 : o1);
    pw[2] = asU(split ? o6 : o2);
    pw[3] = asU(split ? o7 : o3);
  }
  __syncthreads();

  // ---- fused output projection: 8 groups x 8 cols, w_proj scalar ----------
  const int jb2 = __builtin_amdgcn_readfirstlane(tid >> 6);  // wave-uniform
  const int px2 = tid & 63;
  const int j0 = jb2 * 8;
  const int opix = (th * 8 + (px2 >> 3)) * WP + tw * 8 + (px2 & 7);
  float acc[8];
#pragma unroll
  for (int j = 0; j < 8; ++j) acc[j] = 0.f;
  const unsigned int* prow = preLds16 + px2 * PRE16;
#pragma unroll 8
  for (int cp = 0; cp < 32; ++cp) {
    const h2 hh = ash2(prow[cp]);
    const float xc0 = (float)hh[0];
    const float xc1 = (float)hh[1];
    const float* w0 = w_proj + (2 * cp) * 64 + j0;      // scalar rows
    const float* w1 = w_proj + (2 * cp + 1) * 64 + j0;
#pragma unroll
    for (int j = 0; j < 8; ++j)
      acc[j] = fmaf(xc1, w1[j], fmaf(xc0, w0[j], acc[j]));
  }
#pragma unroll
  for (int j = 0; j < 8; ++j) out[(size_t)(j0 + j) * NPIX + opix] = acc[j];
}

extern "C" void kernel_launch(void* const* d_in, const int* in_sizes, int n_in,
                              void* d_out, int out_size, void* d_ws,
                              size_t ws_size, hipStream_t stream) {
  const float* x = (const float*)d_in[0];
  const float* sims = (const float*)d_in[1];
  const float* w_qk = (const float*)d_in[2];
  const float* w_v = (const float*)d_in[3];
  const float* w_proj = (const float*)d_in[4];
  float* out = (float*)d_out;

  unsigned int* qb16 = (unsigned int*)d_ws;
  unsigned int* kb16 = qb16 + (size_t)NPIX * 32;
  unsigned int* vb16 = kb16 + (size_t)NPIX * 32;

  qkv_kernel<<<dim3(3, 576), 256, 0, stream>>>(x, w_qk, w_v, qb16, kb16,
                                               vb16);
  attn_kernel<<<dim3(576), 512, 0, stream>>>(qb16, kb16, vb16, sims, w_proj,
                                             out);
}

// Round 26
// 57.879 us; speedup vs baseline: 16.3840x; 1.6662x over previous
//
#include <hip/hip_runtime.h>
#include <hip/hip_fp16.h>

#define HP 192
#define WP 192
#define NPIX (HP * WP)   // 36864
#define SG 24
#define KSTRU 72         // smK/smV row stride in ushorts (f16): 144 B
#define PI_STRU 12       // smpi16 row stride in uints: 48 B
#define PRE16 33         // preLds16 row stride in uints (f16 pairs)
#define XSTR 36          // qkv xh row stride in uints: 144 B

typedef _Float16 h2 __attribute__((ext_vector_type(2)));

__device__ __forceinline__ unsigned int h2pack(float a, float b) {
  h2 r;
  r[0] = (_Float16)a;
  r[1] = (_Float16)b;
  return __builtin_bit_cast(unsigned int, r);
}
__device__ __forceinline__ h2 ash2(unsigned int u) {
  return __builtin_bit_cast(h2, u);
}
__device__ __forceinline__ __half2 asH2(unsigned int u) {
  return __builtin_bit_cast(__half2, u);
}
__device__ __forceinline__ unsigned int asU(__half2 v) {
  return __builtin_bit_cast(unsigned int, v);
}

// ---------------- Kernel 1: QKV projection, x staged in LDS ------------------
// grid (3, 576), block 256 = 64 px x 4 col-groups. jg forced wave-uniform via
// readfirstlane -> weight addresses scalarize to s_load (r25's per-lane VMEM
// chain at 12% VALU was the 3x regression; r22 proved this s_load pattern
// sustains at 6.75 waves/SIMD). x HBM traffic 113 -> ~10 MB.
__global__ __launch_bounds__(256) void qkv_kernel(
    const float* __restrict__ x,
    const float* __restrict__ w_qk,
    const float* __restrict__ w_v,
    unsigned int* __restrict__ qb16, unsigned int* __restrict__ kb16,
    unsigned int* __restrict__ vb16) {
  __shared__ __align__(16) unsigned int xh[64 * XSTR];  // 9 KB (pad 36)
  const int tid = threadIdx.x;
  const int part = blockIdx.x;       // 0..2  (fast dim -> L2 locality)
  const int px0 = blockIdx.y * 64;

  // stage x: 64 px x 32 ch-pairs, coalesced over px
  for (int i = tid; i < 64 * 32; i += 256) {
    const int px = i & 63, cp = i >> 6;
    const float a = x[(2 * cp) * NPIX + px0 + px];
    const float b = x[(2 * cp + 1) * NPIX + px0 + px];
    xh[px * XSTR + cp] = h2pack(a, b);
  }
  __syncthreads();

  const int px = tid & 63;
  // readfirstlane -> SGPR jg -> scalar weight addressing (s_load broadcast)
  const int jg = part * 4 + __builtin_amdgcn_readfirstlane(tid >> 6);
  const int pix = px0 + px;
  const int j0 = jg * 16;
  const unsigned int* xrow = xh + px * XSTR;

  float acc[16];
#pragma unroll
  for (int j = 0; j < 16; ++j) acc[j] = 0.f;

  if (jg < 8) {
#pragma unroll
    for (int cp = 0; cp < 32; ++cp) {
      const h2 hh = ash2(xrow[cp]);
      const float xc0 = (float)hh[0];
      const float xc1 = (float)hh[1];
      const float* w0 = w_qk + (2 * cp) * 128 + j0;
      const float* w1 = w_qk + (2 * cp + 1) * 128 + j0;
#pragma unroll
      for (int j = 0; j < 16; ++j)
        acc[j] = fmaf(xc1, w1[j], fmaf(xc0, w0[j], acc[j]));
    }
  } else {
#pragma unroll
    for (int cp = 0; cp < 32; ++cp) {
      const h2 hh = ash2(xrow[cp]);
      const float xc0 = (float)hh[0];
      const float xc1 = (float)hh[1];
      const float* w0 = w_v + (2 * cp) * 64 + (j0 - 128);
      const float* w1 = w_v + (2 * cp + 1) * 64 + (j0 - 128);
#pragma unroll
      for (int j = 0; j < 16; ++j)
        acc[j] = fmaf(xc1, w1[j], fmaf(xc0, w0[j], acc[j]));
    }
  }

  unsigned int* dst;
  float mul = 1.0f;
  if (jg < 4) {
    dst = qb16 + (size_t)pix * 32 + j0 / 2;
    mul = 0.25f * 1.44269504089f;  // hd^-0.5 * log2(e)
  } else if (jg < 8) {
    dst = kb16 + (size_t)pix * 32 + (j0 - 64) / 2;
  } else {
    dst = vb16 + (size_t)pix * 32 + (j0 - 128) / 2;
  }
#pragma unroll
  for (int j = 0; j < 8; ++j)
    dst[j] = h2pack(acc[2 * j] * mul, acc[2 * j + 1] * mul);
}

__device__ __forceinline__ float pi_val(const float* __restrict__ sims, int th,
                                        int tw, int r, int c, int s) {
  const int dh = s / 3, dw = s - dh * 3;
  const int shi = th + dh - 1, swj = tw + dw - 1;
  if (shi < 0 || shi >= SG || swj < 0 || swj >= SG || r < 0 || r >= HP ||
      c < 0 || c >= WP)
    return 0.f;
  return sims[((size_t)(r * WP + c)) * (SG * SG) + shi * SG + swj];
}

// ---------------- Kernel 2: attention + fused output projection (r22) --------
__global__ __launch_bounds__(512) void attn_kernel(
    const unsigned int* __restrict__ qb16, const unsigned int* __restrict__ kb16,
    const unsigned int* __restrict__ vb16, const float* __restrict__ sims,
    const float* __restrict__ w_proj, float* __restrict__ out) {
  __shared__ __align__(16) unsigned short smK[196 * KSTRU];
  __shared__ __align__(16) unsigned short smV[196 * KSTRU];
  __shared__ __align__(16) unsigned int smpi16[196 * PI_STRU];
  __shared__ __align__(16) unsigned int preLds16[64 * PRE16];
  const int tile = blockIdx.x;
  const int th = tile / 24, tw = tile % 24;
  const int rowBase = th * 8 - 3, colBase = tw * 8 - 3;
  const int tid = threadIdx.x;

  // ---- stage K and V tiles: straight uint4 copies (f16-packed) ----
  for (int i = tid; i < 196 * 8; i += 512) {
    const int loc = i >> 3, c4 = i & 7;
    const int rl = loc / 14, cl = loc - rl * 14;
    const int r = rowBase + rl, c = colBase + cl;
    uint4 k4 = make_uint4(0u, 0u, 0u, 0u);
    uint4 v4 = make_uint4(0u, 0u, 0u, 0u);
    if (r >= 0 && r < HP && c >= 0 && c < WP) {
      const size_t base = (size_t)(r * WP + c) * 32 + (c4 << 2);
      k4 = *(const uint4*)(kb16 + base);
      v4 = *(const uint4*)(vb16 + base);
    }
    *(uint4*)(smK + loc * KSTRU + (c4 << 3)) = k4;
    *(uint4*)(smV + loc * KSTRU + (c4 << 3)) = v4;
  }
  // ---- stage pi table as f16 pairs: [loc][5 uints] (s8 padded) ----
  for (int i = tid; i < 196 * 5; i += 512) {
    const int loc = i / 5, sp = i - loc * 5;
    const int rl = loc / 14, cl = loc - rl * 14;
    const int r = rowBase + rl, c = colBase + cl;
    const int s0 = sp * 2;
    const float v0 = pi_val(sims, th, tw, r, c, s0);
    const float v1 = (s0 + 1 < 9) ? pi_val(sims, th, tw, r, c, s0 + 1) : 0.f;
    smpi16[loc * PI_STRU + sp] = h2pack(v0, v1);
  }
  __syncthreads();

  const int split = tid & 1;
  const int head = (tid >> 1) & 3;
  const int pl = tid >> 3;  // pixel-in-tile 0..63
  const int py = pl >> 3, px = pl & 7;
  const int h = th * 8 + py, w = tw * 8 + px;
  const int pix = h * WP + w;
  int hs = h - 3;
  hs = hs < 0 ? 0 : (hs > HP - 7 ? HP - 7 : hs);
  int wsb = w - 3;
  wsb = wsb < 0 ? 0 : (wsb > WP - 7 ? WP - 7 : wsb);
  const int rl0 = hs - rowBase;   // 0..7
  const int cl0 = wsb - colBase;  // 0..7
  const int hq = head << 4;       // head base in halves
  const int hu = head << 3;       // head base in uints

  const uint4 qa = *(const uint4*)(qb16 + (size_t)pix * 32 + hu);
  const uint4 qc = *(const uint4*)(qb16 + (size_t)pix * 32 + hu + 4);
  const h2 qh0 = ash2(qa.x), qh1 = ash2(qa.y), qh2 = ash2(qa.z),
           qh3 = ash2(qa.w);
  const h2 qh4 = ash2(qc.x), qh5 = ash2(qc.y), qh6 = ash2(qc.z),
           qh7 = ash2(qc.w);

#define DOT8P(t, kp)                                          \
  {                                                           \
    const uint4 ka = *(const uint4*)(kp);                     \
    const uint4 kc = *(const uint4*)((kp) + 8);               \
    float t0 = 0.f, t1 = 0.f;                                 \
    t0 = __builtin_amdgcn_fdot2(ash2(ka.x), qh0, t0, false);  \
    t0 = __builtin_amdgcn_fdot2(ash2(ka.y), qh1, t0, false);  \
    t0 = __builtin_amdgcn_fdot2(ash2(ka.z), qh2, t0, false);  \
    t0 = __builtin_amdgcn_fdot2(ash2(ka.w), qh3, t0, false);  \
    t1 = __builtin_amdgcn_fdot2(ash2(kc.x), qh4, t1, false);  \
    t1 = __builtin_amdgcn_fdot2(ash2(kc.y), qh5, t1, false);  \
    t1 = __builtin_amdgcn_fdot2(ash2(kc.z), qh6, t1, false);  \
    t1 = __builtin_amdgcn_fdot2(ash2(kc.w), qh7, t1, false);  \
    t = t0 + t1;                                              \
  }

  // ---- pass 1 (FULL unroll): e -> ev[7][4]; partial S, packed D9 ----
  float ev[7][4];
  __half2 D9h0 = __float2half2_rn(0.f), D9h1 = __float2half2_rn(0.f);
  __half2 D9h2 = __float2half2_rn(0.f), D9h3 = __float2half2_rn(0.f);
  float D8 = 0.f, S = 0.f;
#pragma unroll
  for (int kh = 0; kh < 7; ++kh) {
    const int rowloc = (rl0 + kh) * 14 + cl0 + split;
    const unsigned short* krow = smK + rowloc * KSTRU + hq;
    const unsigned int* prow = smpi16 + rowloc * PI_STRU;
#pragma unroll
    for (int j = 0; j < 4; ++j) {
      if (j < 3 || split == 0) {  // kw = 2j+split must be < 7
        float t;
        DOT8P(t, krow + j * (2 * KSTRU))
        const float e = exp2f(t);
        ev[kh][j] = e;
        S += e;
        const unsigned int* pp = prow + j * (2 * PI_STRU);
        const uint4 pu = *(const uint4*)pp;
        const unsigned int p8u = pp[4];
        const __half2 e2 = __float2half2_rn(e);
        D9h0 = __hfma2(e2, asH2(pu.x), D9h0);
        D9h1 = __hfma2(e2, asH2(pu.y), D9h1);
        D9h2 = __hfma2(e2, asH2(pu.z), D9h2);
        D9h3 = __hfma2(e2, asH2(pu.w), D9h3);
        D8 = fmaf(e, (float)ash2(p8u)[0], D8);
      } else {
        ev[kh][j] = 0.f;
      }
    }
  }
#undef DOT8P
  S += __shfl_xor(S, 1);
  D8 += __shfl_xor(D8, 1);
#define COMBH(D) D = __hadd2(D, asH2(__shfl_xor(asU(D), 1)));
  COMBH(D9h0) COMBH(D9h1) COMBH(D9h2) COMBH(D9h3)
#undef COMBH

  // ---- coef_s = ws[s] / (D[s] + 1e-10*S); packed for pass 2 ----
  h2 ch0, ch1, ch2, ch3;
  float c8;
  {
    const unsigned int* pp =
        smpi16 + ((h - rowBase) * 14 + (w - colBase)) * PI_STRU;
    const uint4 pu = *(const uint4*)pp;
    const unsigned int p8u = pp[4];
    const h2 w0 = ash2(pu.x), w1 = ash2(pu.y), w2 = ash2(pu.z),
             w3 = ash2(pu.w);
    const float epsS = 1e-10f * S;
    ch0[0] = (_Float16)((float)w0[0] / (__low2float(D9h0) + epsS));
    ch0[1] = (_Float16)((float)w0[1] / (__high2float(D9h0) + epsS));
    ch1[0] = (_Float16)((float)w1[0] / (__low2float(D9h1) + epsS));
    ch1[1] = (_Float16)((float)w1[1] / (__high2float(D9h1) + epsS));
    ch2[0] = (_Float16)((float)w2[0] / (__low2float(D9h2) + epsS));
    ch2[1] = (_Float16)((float)w2[1] / (__high2float(D9h2) + epsS));
    ch3[0] = (_Float16)((float)w3[0] / (__low2float(D9h3) + epsS));
    ch3[1] = (_Float16)((float)w3[1] / (__high2float(D9h3) + epsS));
    c8 = (float)ash2(p8u)[0] / (D8 + epsS);
  }

  // ---- pass 2 (FULL unroll): NO K/exp2 -- a2 = ev*tc; o += a2*V ----
  __half2 o0 = __float2half2_rn(0.f), o1 = __float2half2_rn(0.f);
  __half2 o2 = __float2half2_rn(0.f), o3 = __float2half2_rn(0.f);
  __half2 o4 = __float2half2_rn(0.f), o5 = __float2half2_rn(0.f);
  __half2 o6 = __float2half2_rn(0.f), o7 = __float2half2_rn(0.f);
#pragma unroll
  for (int kh = 0; kh < 7; ++kh) {
    const int rowloc = (rl0 + kh) * 14 + cl0 + split;
    const unsigned short* vrow = smV + rowloc * KSTRU + hq;
    const unsigned int* prow = smpi16 + rowloc * PI_STRU;
#pragma unroll
    for (int j = 0; j < 4; ++j) {
      if (j < 3 || split == 0) {
        const unsigned int* pp = prow + j * (2 * PI_STRU);
        const uint4 pu = *(const uint4*)pp;
        const unsigned int p8u = pp[4];
        float tA = __builtin_amdgcn_fdot2(ash2(pu.x), ch0, 0.f, false);
        tA = __builtin_amdgcn_fdot2(ash2(pu.y), ch1, tA, false);
        float tB = __builtin_amdgcn_fdot2(ash2(pu.z), ch2, 0.f, false);
        tB = __builtin_amdgcn_fdot2(ash2(pu.w), ch3, tB, false);
        const float tc = (tA + tB) + c8 * (float)ash2(p8u)[0];
        const __half2 a2 = __float2half2_rn(ev[kh][j] * tc);
        const unsigned short* vp = vrow + j * (2 * KSTRU);
        const uint4 va = *(const uint4*)vp;
        const uint4 vc = *(const uint4*)(vp + 8);
        o0 = __hfma2(a2, asH2(va.x), o0);
        o1 = __hfma2(a2, asH2(va.y), o1);
        o2 = __hfma2(a2, asH2(va.z), o2);
        o3 = __hfma2(a2, asH2(va.w), o3);
        o4 = __hfma2(a2, asH2(vc.x), o4);
        o5 = __hfma2(a2, asH2(vc.y), o5);
        o6 = __hfma2(a2, asH2(vc.z), o6);
        o7 = __hfma2(a2, asH2(vc.w), o7);
      }
    }
  }

  // ---- combine lane pair (packed); write to preLds16 ----
#define COMBO(x) x = __hadd2(x, asH2(__shfl_xor(asU(x), 1)));
  COMBO(o0) COMBO(o1) COMBO(o2) COMBO(o3)
  COMBO(o4) COMBO(o5) COMBO(o6) COMBO(o7)
#undef COMBO
  {
    unsigned int* pw = preLds16 + pl * PRE16 + hu + split * 4;
    pw[0] = asU(split ? o4 : o0);
    pw[1] = asU(split ? o5 : o1);
    pw[2] = asU(split ? o6 : o2);
    pw[3] = asU(split ? o7 : o3);
  }
  __syncthreads();

  // ---- fused output projection: 8 groups x 8 cols, w_proj scalar ----------
  const int jb2 = __builtin_amdgcn_readfirstlane(tid >> 6);  // wave-uniform
  const int px2 = tid & 63;
  const int j0 = jb2 * 8;
  const int opix = (th * 8 + (px2 >> 3)) * WP + tw * 8 + (px2 & 7);
  float acc[8];
#pragma unroll
  for (int j = 0; j < 8; ++j) acc[j] = 0.f;
  const unsigned int* prow = preLds16 + px2 * PRE16;
#pragma unroll 8
  for (int cp = 0; cp < 32; ++cp) {
    const h2 hh = ash2(prow[cp]);
    const float xc0 = (float)hh[0];
    const float xc1 = (float)hh[1];
    const float* w0 = w_proj + (2 * cp) * 64 + j0;      // scalar rows
    const float* w1 = w_proj + (2 * cp + 1) * 64 + j0;
#pragma unroll
    for (int j = 0; j < 8; ++j)
      acc[j] = fmaf(xc1, w1[j], fmaf(xc0, w0[j], acc[j]));
  }
#pragma unroll
  for (int j = 0; j < 8; ++j) out[(size_t)(j0 + j) * NPIX + opix] = acc[j];
}

extern "C" void kernel_launch(void* const* d_in, const int* in_sizes, int n_in,
                              void* d_out, int out_size, void* d_ws,
                              size_t ws_size, hipStream_t stream) {
  const float* x = (const float*)d_in[0];
  const float* sims = (const float*)d_in[1];
  const float* w_qk = (const float*)d_in[2];
  const float* w_v = (const float*)d_in[3];
  const float* w_proj = (const float*)d_in[4];
  float* out = (float*)d_out;

  unsigned int* qb16 = (unsigned int*)d_ws;
  unsigned int* kb16 = qb16 + (size_t)NPIX * 32;
  unsigned int* vb16 = kb16 + (size_t)NPIX * 32;

  qkv_kernel<<<dim3(3, 576), 256, 0, stream>>>(x, w_qk, w_v, qb16, kb16,
                                               vb16);
  attn_kernel<<<dim3(576), 512, 0, stream>>>(qb16, kb16, vb16, sims, w_proj,
                                             out);
}

// Round 27
// 56.132 us; speedup vs baseline: 16.8940x; 1.0311x over previous
//
#include <hip/hip_runtime.h>
#include <hip/hip_fp16.h>

#define HP 192
#define WP 192
#define NPIX (HP * WP)   // 36864
#define SG 24
#define KSTRU 72         // smK/smV row stride in ushorts (f16): 144 B
#define PI_STRU 12       // smpi16 row stride in uints: 48 B
#define PRE16 33         // preLds16 row stride in uints (f16 pairs)
#define XSTR 36          // qkv xh row stride in uints: 144 B

typedef _Float16 h2 __attribute__((ext_vector_type(2)));

__device__ __forceinline__ unsigned int h2pack(float a, float b) {
  h2 r;
  r[0] = (_Float16)a;
  r[1] = (_Float16)b;
  return __builtin_bit_cast(unsigned int, r);
}
__device__ __forceinline__ h2 ash2(unsigned int u) {
  return __builtin_bit_cast(h2, u);
}
__device__ __forceinline__ __half2 asH2(unsigned int u) {
  return __builtin_bit_cast(__half2, u);
}
__device__ __forceinline__ unsigned int asU(__half2 v) {
  return __builtin_bit_cast(unsigned int, v);
}

// ---------------- Kernel 1: QKV projection, x staged in LDS (r26) ------------
__global__ __launch_bounds__(256) void qkv_kernel(
    const float* __restrict__ x,
    const float* __restrict__ w_qk,
    const float* __restrict__ w_v,
    unsigned int* __restrict__ qb16, unsigned int* __restrict__ kb16,
    unsigned int* __restrict__ vb16) {
  __shared__ __align__(16) unsigned int xh[64 * XSTR];  // 9 KB (pad 36)
  const int tid = threadIdx.x;
  const int part = blockIdx.x;       // 0..2  (fast dim -> L2 locality)
  const int px0 = blockIdx.y * 64;

  // stage x: 64 px x 32 ch-pairs, coalesced over px
  for (int i = tid; i < 64 * 32; i += 256) {
    const int px = i & 63, cp = i >> 6;
    const float a = x[(2 * cp) * NPIX + px0 + px];
    const float b = x[(2 * cp + 1) * NPIX + px0 + px];
    xh[px * XSTR + cp] = h2pack(a, b);
  }
  __syncthreads();

  const int px = tid & 63;
  // readfirstlane -> SGPR jg -> scalar weight addressing (s_load broadcast)
  const int jg = part * 4 + __builtin_amdgcn_readfirstlane(tid >> 6);
  const int pix = px0 + px;
  const int j0 = jg * 16;
  const unsigned int* xrow = xh + px * XSTR;

  float acc[16];
#pragma unroll
  for (int j = 0; j < 16; ++j) acc[j] = 0.f;

  if (jg < 8) {
#pragma unroll
    for (int cp = 0; cp < 32; ++cp) {
      const h2 hh = ash2(xrow[cp]);
      const float xc0 = (float)hh[0];
      const float xc1 = (float)hh[1];
      const float* w0 = w_qk + (2 * cp) * 128 + j0;
      const float* w1 = w_qk + (2 * cp + 1) * 128 + j0;
#pragma unroll
      for (int j = 0; j < 16; ++j)
        acc[j] = fmaf(xc1, w1[j], fmaf(xc0, w0[j], acc[j]));
    }
  } else {
#pragma unroll
    for (int cp = 0; cp < 32; ++cp) {
      const h2 hh = ash2(xrow[cp]);
      const float xc0 = (float)hh[0];
      const float xc1 = (float)hh[1];
      const float* w0 = w_v + (2 * cp) * 64 + (j0 - 128);
      const float* w1 = w_v + (2 * cp + 1) * 64 + (j0 - 128);
#pragma unroll
      for (int j = 0; j < 16; ++j)
        acc[j] = fmaf(xc1, w1[j], fmaf(xc0, w0[j], acc[j]));
    }
  }

  unsigned int* dst;
  float mul = 1.0f;
  if (jg < 4) {
    dst = qb16 + (size_t)pix * 32 + j0 / 2;
    mul = 0.25f * 1.44269504089f;  // hd^-0.5 * log2(e)
  } else if (jg < 8) {
    dst = kb16 + (size_t)pix * 32 + (j0 - 64) / 2;
  } else {
    dst = vb16 + (size_t)pix * 32 + (j0 - 128) / 2;
  }
#pragma unroll
  for (int j = 0; j < 8; ++j)
    dst[j] = h2pack(acc[2 * j] * mul, acc[2 * j + 1] * mul);
}

__device__ __forceinline__ float pi_val(const float* __restrict__ sims, int th,
                                        int tw, int r, int c, int s) {
  const int dh = s / 3, dw = s - dh * 3;
  const int shi = th + dh - 1, swj = tw + dw - 1;
  if (shi < 0 || shi >= SG || swj < 0 || swj >= SG || r < 0 || r >= HP ||
      c < 0 || c >= WP)
    return 0.f;
  return sims[((size_t)(r * WP + c)) * (SG * SG) + shi * SG + swj];
}

// ---------------- Kernel 2: attention + fused output projection --------------
// r26 + XCD-chunked tile swizzle (T1): 72 consecutive tiles (3 full tile-rows)
// per XCD so horizontally AND vertically adjacent tiles share per-XCD L2 for
// their overlapping K/V halos. 576 % 8 == 0 -> bijective.
__global__ __launch_bounds__(512) void attn_kernel(
    const unsigned int* __restrict__ qb16, const unsigned int* __restrict__ kb16,
    const unsigned int* __restrict__ vb16, const float* __restrict__ sims,
    const float* __restrict__ w_proj, float* __restrict__ out) {
  __shared__ __align__(16) unsigned short smK[196 * KSTRU];
  __shared__ __align__(16) unsigned short smV[196 * KSTRU];
  __shared__ __align__(16) unsigned int smpi16[196 * PI_STRU];
  __shared__ __align__(16) unsigned int preLds16[64 * PRE16];
  const int bid = blockIdx.x;
  const int tile = (bid & 7) * 72 + (bid >> 3);  // XCD-chunked swizzle
  const int th = tile / 24, tw = tile % 24;
  const int rowBase = th * 8 - 3, colBase = tw * 8 - 3;
  const int tid = threadIdx.x;

  // ---- stage K and V tiles: straight uint4 copies (f16-packed) ----
  for (int i = tid; i < 196 * 8; i += 512) {
    const int loc = i >> 3, c4 = i & 7;
    const int rl = loc / 14, cl = loc - rl * 14;
    const int r = rowBase + rl, c = colBase + cl;
    uint4 k4 = make_uint4(0u, 0u, 0u, 0u);
    uint4 v4 = make_uint4(0u, 0u, 0u, 0u);
    if (r >= 0 && r < HP && c >= 0 && c < WP) {
      const size_t base = (size_t)(r * WP + c) * 32 + (c4 << 2);
      k4 = *(const uint4*)(kb16 + base);
      v4 = *(const uint4*)(vb16 + base);
    }
    *(uint4*)(smK + loc * KSTRU + (c4 << 3)) = k4;
    *(uint4*)(smV + loc * KSTRU + (c4 << 3)) = v4;
  }
  // ---- stage pi table as f16 pairs: [loc][5 uints] (s8 padded) ----
  for (int i = tid; i < 196 * 5; i += 512) {
    const int loc = i / 5, sp = i - loc * 5;
    const int rl = loc / 14, cl = loc - rl * 14;
    const int r = rowBase + rl, c = colBase + cl;
    const int s0 = sp * 2;
    const float v0 = pi_val(sims, th, tw, r, c, s0);
    const float v1 = (s0 + 1 < 9) ? pi_val(sims, th, tw, r, c, s0 + 1) : 0.f;
    smpi16[loc * PI_STRU + sp] = h2pack(v0, v1);
  }
  __syncthreads();

  const int split = tid & 1;
  const int head = (tid >> 1) & 3;
  const int pl = tid >> 3;  // pixel-in-tile 0..63
  const int py = pl >> 3, px = pl & 7;
  const int h = th * 8 + py, w = tw * 8 + px;
  const int pix = h * WP + w;
  int hs = h - 3;
  hs = hs < 0 ? 0 : (hs > HP - 7 ? HP - 7 : hs);
  int wsb = w - 3;
  wsb = wsb < 0 ? 0 : (wsb > WP - 7 ? WP - 7 : wsb);
  const int rl0 = hs - rowBase;   // 0..7
  const int cl0 = wsb - colBase;  // 0..7
  const int hq = head << 4;       // head base in halves
  const int hu = head << 3;       // head base in uints

  const uint4 qa = *(const uint4*)(qb16 + (size_t)pix * 32 + hu);
  const uint4 qc = *(const uint4*)(qb16 + (size_t)pix * 32 + hu + 4);
  const h2 qh0 = ash2(qa.x), qh1 = ash2(qa.y), qh2 = ash2(qa.z),
           qh3 = ash2(qa.w);
  const h2 qh4 = ash2(qc.x), qh5 = ash2(qc.y), qh6 = ash2(qc.z),
           qh7 = ash2(qc.w);

#define DOT8P(t, kp)                                          \
  {                                                           \
    const uint4 ka = *(const uint4*)(kp);                     \
    const uint4 kc = *(const uint4*)((kp) + 8);               \
    float t0 = 0.f, t1 = 0.f;                                 \
    t0 = __builtin_amdgcn_fdot2(ash2(ka.x), qh0, t0, false);  \
    t0 = __builtin_amdgcn_fdot2(ash2(ka.y), qh1, t0, false);  \
    t0 = __builtin_amdgcn_fdot2(ash2(ka.z), qh2, t0, false);  \
    t0 = __builtin_amdgcn_fdot2(ash2(ka.w), qh3, t0, false);  \
    t1 = __builtin_amdgcn_fdot2(ash2(kc.x), qh4, t1, false);  \
    t1 = __builtin_amdgcn_fdot2(ash2(kc.y), qh5, t1, false);  \
    t1 = __builtin_amdgcn_fdot2(ash2(kc.z), qh6, t1, false);  \
    t1 = __builtin_amdgcn_fdot2(ash2(kc.w), qh7, t1, false);  \
    t = t0 + t1;                                              \
  }

  // ---- pass 1 (FULL unroll): e -> ev[7][4]; partial S, packed D9 ----
  float ev[7][4];
  __half2 D9h0 = __float2half2_rn(0.f), D9h1 = __float2half2_rn(0.f);
  __half2 D9h2 = __float2half2_rn(0.f), D9h3 = __float2half2_rn(0.f);
  float D8 = 0.f, S = 0.f;
#pragma unroll
  for (int kh = 0; kh < 7; ++kh) {
    const int rowloc = (rl0 + kh) * 14 + cl0 + split;
    const unsigned short* krow = smK + rowloc * KSTRU + hq;
    const unsigned int* prow = smpi16 + rowloc * PI_STRU;
#pragma unroll
    for (int j = 0; j < 4; ++j) {
      if (j < 3 || split == 0) {  // kw = 2j+split must be < 7
        float t;
        DOT8P(t, krow + j * (2 * KSTRU))
        const float e = exp2f(t);
        ev[kh][j] = e;
        S += e;
        const unsigned int* pp = prow + j * (2 * PI_STRU);
        const uint4 pu = *(const uint4*)pp;
        const unsigned int p8u = pp[4];
        const __half2 e2 = __float2half2_rn(e);
        D9h0 = __hfma2(e2, asH2(pu.x), D9h0);
        D9h1 = __hfma2(e2, asH2(pu.y), D9h1);
        D9h2 = __hfma2(e2, asH2(pu.z), D9h2);
        D9h3 = __hfma2(e2, asH2(pu.w), D9h3);
        D8 = fmaf(e, (float)ash2(p8u)[0], D8);
      } else {
        ev[kh][j] = 0.f;
      }
    }
  }
#undef DOT8P
  S += __shfl_xor(S, 1);
  D8 += __shfl_xor(D8, 1);
#define COMBH(D) D = __hadd2(D, asH2(__shfl_xor(asU(D), 1)));
  COMBH(D9h0) COMBH(D9h1) COMBH(D9h2) COMBH(D9h3)
#undef COMBH

  // ---- coef_s = ws[s] / (D[s] + 1e-10*S); packed for pass 2 ----
  h2 ch0, ch1, ch2, ch3;
  float c8;
  {
    const unsigned int* pp =
        smpi16 + ((h - rowBase) * 14 + (w - colBase)) * PI_STRU;
    const uint4 pu = *(const uint4*)pp;
    const unsigned int p8u = pp[4];
    const h2 w0 = ash2(pu.x), w1 = ash2(pu.y), w2 = ash2(pu.z),
             w3 = ash2(pu.w);
    const float epsS = 1e-10f * S;
    ch0[0] = (_Float16)((float)w0[0] / (__low2float(D9h0) + epsS));
    ch0[1] = (_Float16)((float)w0[1] / (__high2float(D9h0) + epsS));
    ch1[0] = (_Float16)((float)w1[0] / (__low2float(D9h1) + epsS));
    ch1[1] = (_Float16)((float)w1[1] / (__high2float(D9h1) + epsS));
    ch2[0] = (_Float16)((float)w2[0] / (__low2float(D9h2) + epsS));
    ch2[1] = (_Float16)((float)w2[1] / (__high2float(D9h2) + epsS));
    ch3[0] = (_Float16)((float)w3[0] / (__low2float(D9h3) + epsS));
    ch3[1] = (_Float16)((float)w3[1] / (__high2float(D9h3) + epsS));
    c8 = (float)ash2(p8u)[0] / (D8 + epsS);
  }

  // ---- pass 2 (FULL unroll): NO K/exp2 -- a2 = ev*tc; o += a2*V ----
  __half2 o0 = __float2half2_rn(0.f), o1 = __float2half2_rn(0.f);
  __half2 o2 = __float2half2_rn(0.f), o3 = __float2half2_rn(0.f);
  __half2 o4 = __float2half2_rn(0.f), o5 = __float2half2_rn(0.f);
  __half2 o6 = __float2half2_rn(0.f), o7 = __float2half2_rn(0.f);
#pragma unroll
  for (int kh = 0; kh < 7; ++kh) {
    const int rowloc = (rl0 + kh) * 14 + cl0 + split;
    const unsigned short* vrow = smV + rowloc * KSTRU + hq;
    const unsigned int* prow = smpi16 + rowloc * PI_STRU;
#pragma unroll
    for (int j = 0; j < 4; ++j) {
      if (j < 3 || split == 0) {
        const unsigned int* pp = prow + j * (2 * PI_STRU);
        const uint4 pu = *(const uint4*)pp;
        const unsigned int p8u = pp[4];
        float tA = __builtin_amdgcn_fdot2(ash2(pu.x), ch0, 0.f, false);
        tA = __builtin_amdgcn_fdot2(ash2(pu.y), ch1, tA, false);
        float tB = __builtin_amdgcn_fdot2(ash2(pu.z), ch2, 0.f, false);
        tB = __builtin_amdgcn_fdot2(ash2(pu.w), ch3, tB, false);
        const float tc = (tA + tB) + c8 * (float)ash2(p8u)[0];
        const __half2 a2 = __float2half2_rn(ev[kh][j] * tc);
        const unsigned short* vp = vrow + j * (2 * KSTRU);
        const uint4 va = *(const uint4*)vp;
        const uint4 vc = *(const uint4*)(vp + 8);
        o0 = __hfma2(a2, asH2(va.x), o0);
        o1 = __hfma2(a2, asH2(va.y), o1);
        o2 = __hfma2(a2, asH2(va.z), o2);
        o3 = __hfma2(a2, asH2(va.w), o3);
        o4 = __hfma2(a2, asH2(vc.x), o4);
        o5 = __hfma2(a2, asH2(vc.y), o5);
        o6 = __hfma2(a2, asH2(vc.z), o6);
        o7 = __hfma2(a2, asH2(vc.w), o7);
      }
    }
  }

  // ---- combine lane pair (packed); write to preLds16 ----
#define COMBO(x) x = __hadd2(x, asH2(__shfl_xor(asU(x), 1)));
  COMBO(o0) COMBO(o1) COMBO(o2) COMBO(o3)
  COMBO(o4) COMBO(o5) COMBO(o6) COMBO(o7)
#undef COMBO
  {
    unsigned int* pw = preLds16 + pl * PRE16 + hu + split * 4;
    pw[0] = asU(split ? o4 : o0);
    pw[1] = asU(split ? o5 : o1);
    pw[2] = asU(split ? o6 : o2);
    pw[3] = asU(split ? o7 : o3);
  }
  __syncthreads();

  // ---- fused output projection: 8 groups x 8 cols, w_proj scalar ----------
  const int jb2 = __builtin_amdgcn_readfirstlane(tid >> 6);  // wave-uniform
  const int px2 = tid & 63;
  const int j0 = jb2 * 8;
  const int opix = (th * 8 + (px2 >> 3)) * WP + tw * 8 + (px2 & 7);
  float acc[8];
#pragma unroll
  for (int j = 0; j < 8; ++j) acc[j] = 0.f;
  const unsigned int* prow = preLds16 + px2 * PRE16;
#pragma unroll 8
  for (int cp = 0; cp < 32; ++cp) {
    const h2 hh = ash2(prow[cp]);
    const float xc0 = (float)hh[0];
    const float xc1 = (float)hh[1];
    const float* w0 = w_proj + (2 * cp) * 64 + j0;      // scalar rows
    const float* w1 = w_proj + (2 * cp + 1) * 64 + j0;
#pragma unroll
    for (int j = 0; j < 8; ++j)
      acc[j] = fmaf(xc1, w1[j], fmaf(xc0, w0[j], acc[j]));
  }
#pragma unroll
  for (int j = 0; j < 8; ++j) out[(size_t)(j0 + j) * NPIX + opix] = acc[j];
}

extern "C" void kernel_launch(void* const* d_in, const int* in_sizes, int n_in,
                              void* d_out, int out_size, void* d_ws,
                              size_t ws_size, hipStream_t stream) {
  const float* x = (const float*)d_in[0];
  const float* sims = (const float*)d_in[1];
  const float* w_qk = (const float*)d_in[2];
  const float* w_v = (const float*)d_in[3];
  const float* w_proj = (const float*)d_in[4];
  float* out = (float*)d_out;

  unsigned int* qb16 = (unsigned int*)d_ws;
  unsigned int* kb16 = qb16 + (size_t)NPIX * 32;
  unsigned int* vb16 = kb16 + (size_t)NPIX * 32;

  qkv_kernel<<<dim3(3, 576), 256, 0, stream>>>(x, w_qk, w_v, qb16, kb16,
                                               vb16);
  attn_kernel<<<dim3(576), 512, 0, stream>>>(qb16, kb16, vb16, sims, w_proj,
                                             out);
}